// Round 1
// baseline (473.829 us; speedup 1.0000x reference)
//
#include <hip/hip_runtime.h>

// Periodic padding expressed as two selector-matrix GEMMs in the reference:
//   out[b,c,i,j] = x[b,c,(i-2) mod 512, (j-2) mod 512]
// B=32, C=8, H=W=512, ELP=ERP=2 -> out is (32,8,516,516) fp32.
// Pure memory-bound gather/copy: ~256 MiB read + ~260 MiB write.

#define Hdim 512
#define Wdim 512
#define BC   256            // B*C = 32*8
#define OH   516            // H + ELP + ERP
#define OW   516
#define NROWS (BC * OH)     // 132096 output rows

__global__ __launch_bounds__(256) void periodic_pad_kernel(
    const float* __restrict__ x, float* __restrict__ out) {
    const int t = threadIdx.x;
    for (int row = blockIdx.x; row < NROWS; row += gridDim.x) {
        const int bc = row / OH;
        const int i  = row - bc * OH;
        const int si = (i + Hdim - 2) & (Hdim - 1);   // (i-2) mod 512, H is pow2
        const float* __restrict__ src = x + ((size_t)bc * Hdim + (size_t)si) * Wdim;
        float*       __restrict__ dst = out + (size_t)row * OW;

        // Interior: dst[2 + 2t .. 2 + 2t + 2) = src[2t .. 2t + 2)
        // Row byte offsets: dst row start = row*2064 (16B-aligned); dst+2+2t is
        // 8B-aligned; src row start = 2048-multiple; src+2t is 8B-aligned.
        const float2 v = *reinterpret_cast<const float2*>(src + 2 * t);
        *reinterpret_cast<float2*>(dst + 2 + 2 * t) = v;

        // Halo columns (4 per row): wrap-around from the far side.
        if (t == 0) {
            // dst[0..2) = src[510..512)
            *reinterpret_cast<float2*>(dst) =
                *reinterpret_cast<const float2*>(src + Wdim - 2);
        } else if (t == 1) {
            // dst[514..516) = src[0..2)
            *reinterpret_cast<float2*>(dst + OW - 2) =
                *reinterpret_cast<const float2*>(src);
        }
    }
}

extern "C" void kernel_launch(void* const* d_in, const int* in_sizes, int n_in,
                              void* d_out, int out_size, void* d_ws, size_t ws_size,
                              hipStream_t stream) {
    const float* x   = (const float*)d_in[0];   // (32,8,512,512) fp32
    float*       out = (float*)d_out;           // (32,8,516,516) fp32
    // M_mat (d_in[1]) and N_mat (d_in[2]) are fixed selector matrices; their
    // action is hard-coded as the (i-2) mod 512 gather above.

    const int block = 256;
    const int grid  = 2048;   // grid-stride over 132096 rows (~64 iters/block)
    periodic_pad_kernel<<<grid, block, 0, stream>>>(x, out);
}